// Round 2
// baseline (146.510 us; speedup 1.0000x reference)
//
#include <hip/hip_runtime.h>
#include <hip/hip_bf16.h>

// Problem constants (match the JAX reference).
#define BB     16
#define QQ     2048
#define NCLS   2
#define DBOX   6
#define TT     1024
#define ROWS   (BB * QQ)          // 32768 (b,q) rows
#define TPB    256                // threads per block
#define TPT    4                  // targets per thread: 256*4 = 1024 = TT
#define RPB    16                 // rows per block: grid = 32768/16 = 2048 blocks

__global__ __launch_bounds__(TPB) void hungarian_cost_kernel(
    const float* __restrict__ logits,   // (ROWS, NCLS) f32
    const float* __restrict__ boxes,    // (ROWS, DBOX) f32
    const int*   __restrict__ labels,   // (TT,) int32
    const float* __restrict__ tboxes,   // (TT, DBOX) f32
    float*       __restrict__ out)      // (ROWS, TT) f32
{
    const int tid = threadIdx.x;
    const int t0  = tid * TPT;

    // --- Preload this thread's 4 targets into registers (one time) ---
    float tb[TPT][DBOX];
    float w[TPT];
#pragma unroll
    for (int j = 0; j < TPT; ++j) {
        const int t = t0 + j;
#pragma unroll
        for (int d = 0; d < DBOX; ++d) tb[j][d] = tboxes[t * DBOX + d];
        w[j] = (float)labels[t];    // label in {0,1} -> selector weight
    }

    const int row0 = blockIdx.x * RPB;

#pragma unroll 1
    for (int r = 0; r < RPB; ++r) {
        const int row = row0 + r;   // wave-uniform -> scalar loads

        // 2-class softmax: p[label] = p0 + label*(p1-p0)
        const float l0  = logits[row * NCLS + 0];
        const float l1  = logits[row * NCLS + 1];
        const float e0  = __expf(l0);
        const float e1  = __expf(l1);
        const float inv = 1.0f / (e0 + e1);
        const float p0  = e0 * inv;
        const float d10 = (e1 - e0) * inv;   // p1 - p0

        float qb[DBOX];
#pragma unroll
        for (int d = 0; d < DBOX; ++d) qb[d] = boxes[row * DBOX + d];

        float c[TPT];
#pragma unroll
        for (int j = 0; j < TPT; ++j) {
            float s = 0.0f;
#pragma unroll
            for (int d = 0; d < DBOX; ++d) s += fabsf(qb[d] - tb[j][d]);
            c[j] = 5.0f * s - (p0 + w[j] * d10);
        }

        float4 v = make_float4(c[0], c[1], c[2], c[3]);
        *reinterpret_cast<float4*>(out + (size_t)row * TT + t0) = v;  // 16B aligned
    }
}

extern "C" void kernel_launch(void* const* d_in, const int* in_sizes, int n_in,
                              void* d_out, int out_size, void* d_ws, size_t ws_size,
                              hipStream_t stream) {
    const float* logits = (const float*)d_in[0];   // (B,Q,NCLS) f32
    const float* boxes  = (const float*)d_in[1];   // (B,Q,DBOX) f32
    const int*   labels = (const int*)  d_in[2];   // (T,) int
    const float* tboxes = (const float*)d_in[3];   // (T,DBOX) f32
    float*       out    = (float*)d_out;           // (B,Q,T) f32

    const int grid = ROWS / RPB;  // 2048
    hungarian_cost_kernel<<<grid, TPB, 0, stream>>>(logits, boxes, labels, tboxes, out);
}